// Round 1
// baseline (1405.550 us; speedup 1.0000x reference)
//
#include <hip/hip_runtime.h>

#define T_SEQ 25
#define NBATCH 4096
#define D_IN 500
#define HID 64
#define NG 256
#define NLAYERS 25
#define NOUT 10

typedef __attribute__((ext_vector_type(8))) short bf16x8;
typedef __attribute__((ext_vector_type(4))) float f32x4;

__device__ __forceinline__ short f2bf(float f) {
    union { float f; unsigned u; } v; v.f = f;
    unsigned u = v.u + 0x7FFFu + ((v.u >> 16) & 1u);   // RNE
    return (short)(u >> 16);
}
__device__ __forceinline__ float bf2f(short s) {
    union { unsigned u; float f; } v;
    v.u = ((unsigned)(unsigned short)s) << 16;
    return v.f;
}
__device__ __forceinline__ bf16x8 cvt8(f32x4 a, f32x4 b) {
    bf16x8 r;
    r[0]=f2bf(a[0]); r[1]=f2bf(a[1]); r[2]=f2bf(a[2]); r[3]=f2bf(a[3]);
    r[4]=f2bf(b[0]); r[5]=f2bf(b[1]); r[6]=f2bf(b[2]); r[7]=f2bf(b[3]);
    return r;
}
__device__ __forceinline__ bf16x8 load_w8(const float* p) {
    const f32x4* p4 = (const f32x4*)p;
    return cvt8(p4[0], p4[1]);
}
__device__ __forceinline__ float sigm(float x)  { return 1.f/(1.f + __expf(-x)); }
__device__ __forceinline__ float tanh_f(float x){ return 1.f - 2.f/(__expf(2.f*x) + 1.f); }

// ---------------------------------------------------------------------------
// Kernel A: xp0[t][g][b] = sum_k x[t][b][k]*Wih0[g][k] + bih0[g] + bhh0[g]
// M-tile 128 (b within one t), N = 256 full, K = 500 padded to 512.
// Output layout [t][g][b] fp32 so kernel B reads 16B/lane contiguous in b.
// ---------------------------------------------------------------------------
__global__ __launch_bounds__(256, 1)
void xp0_gemm(const float* __restrict__ x, const float* __restrict__ Wih0,
              const float* __restrict__ bih0, const float* __restrict__ bhh0,
              float* __restrict__ xp0) {
    __shared__ short a_sh[128][40];   // pad 32->40 shorts to break bank stride
    __shared__ short b_sh[256][40];
    const int tid  = threadIdx.x;
    const int wv   = tid >> 6, lane = tid & 63, col = lane & 15, q = lane >> 4;
    const int t    = blockIdx.x >> 5;          // 32 M-tiles per t
    const int b0   = (blockIdx.x & 31) << 7;   // 128-row b tile

    f32x4 acc[2][16];
    #pragma unroll
    for (int nt = 0; nt < 16; nt++) {
        int g = nt*16 + col;
        float bv = bih0[g] + bhh0[g];
        acc[0][nt] = (f32x4){bv,bv,bv,bv};
        acc[1][nt] = acc[0][nt];
    }

    const int arow = tid >> 1;
    const int akh  = (tid & 1) << 4;           // 0 or 16
    const float* axp = x + ((size_t)t*NBATCH + b0 + arow)*D_IN + akh;
    const float* bwp = Wih0 + (size_t)tid*D_IN;

    #pragma unroll 1
    for (int kc = 0; kc < 16; kc++) {
        const int kb = kc*32;
        if (kc < 15) {                          // fully in-bounds (k <= 479+31 < 500? yes: 479)
            const f32x4* s = (const f32x4*)(axp + kb);
            f32x4 v0 = s[0], v1 = s[1], v2 = s[2], v3 = s[3];
            *(bf16x8*)&a_sh[arow][akh]     = cvt8(v0, v1);
            *(bf16x8*)&a_sh[arow][akh + 8] = cvt8(v2, v3);
            const f32x4* sb = (const f32x4*)(bwp + kb);
            #pragma unroll
            for (int j = 0; j < 4; j++) {
                f32x4 u0 = sb[2*j], u1 = sb[2*j+1];
                *(bf16x8*)&b_sh[tid][j*8] = cvt8(u0, u1);
            }
        } else {                                // K tail: 480..511, valid < 500
            #pragma unroll
            for (int i = 0; i < 16; i++) {
                int k = kb + akh + i;
                a_sh[arow][akh + i] = (k < D_IN) ? f2bf(axp[kb + i]) : (short)0;
            }
            #pragma unroll
            for (int i = 0; i < 32; i++) {
                int k = kb + i;
                b_sh[tid][i] = (k < D_IN) ? f2bf(bwp[kb + i]) : (short)0;
            }
        }
        __syncthreads();
        bf16x8 a0 = *(const bf16x8*)&a_sh[wv*32      + col][q*8];
        bf16x8 a1 = *(const bf16x8*)&a_sh[wv*32 + 16 + col][q*8];
        #pragma unroll
        for (int nt = 0; nt < 16; nt++) {
            bf16x8 bf = *(const bf16x8*)&b_sh[nt*16 + col][q*8];
            acc[0][nt] = __builtin_amdgcn_mfma_f32_16x16x32_bf16(a0, bf, acc[0][nt], 0,0,0);
            acc[1][nt] = __builtin_amdgcn_mfma_f32_16x16x32_bf16(a1, bf, acc[1][nt], 0,0,0);
        }
        __syncthreads();
    }
    // epilogue: D lane (q,col) holds rows m=4q+r, col n -> b = ...+4q+r contiguous
    #pragma unroll
    for (int ms = 0; ms < 2; ms++) {
        #pragma unroll
        for (int nt = 0; nt < 16; nt++) {
            int g = nt*16 + col;
            int b = b0 + wv*32 + ms*16 + q*4;
            *(f32x4*)(xp0 + ((size_t)t*NG + g)*NBATCH + b) = acc[ms][nt];
        }
    }
}

// ---------------------------------------------------------------------------
// Kernel B: persistent per-batch-slice LSTM. 256 WGs x 256 thr; WG owns 16
// batch rows for all 25 layers x 25 timesteps. Wave w owns h-slice
// [16w,16w+16): its 4 N-tiles are the 4 gate types for those h, so the
// gate nonlinearity is fully in-register (no cross-wave exchange).
// h sequence lives in ONE in-place LDS buffer (bf16, A-fragment layout).
// ---------------------------------------------------------------------------
__global__ __launch_bounds__(256, 1)
void lstm_persist(const float* __restrict__ Whh0,
                  const float* __restrict__ WihR, const float* __restrict__ WhhR,
                  const float* __restrict__ bihR, const float* __restrict__ bhhR,
                  const float* __restrict__ Wlin, const float* __restrict__ blin,
                  const float* __restrict__ xp0, float* __restrict__ out) {
    __shared__ short seq[T_SEQ][16][72];   // [t][b][h] bf16, h-stride padded 64->72
    const int tid = threadIdx.x;
    const int wv  = tid >> 6, lane = tid & 63, col = lane & 15, q = lane >> 4;
    const int b0  = blockIdx.x << 4;
    const int hh  = wv*16 + col;           // this lane's h (and gate column)
    float* __restrict__ h_n = out + 250;
    float* __restrict__ c_n = out + 250 + (size_t)NLAYERS*NBATCH*HID;

    bf16x8 wih[4][2], whh[4][2];
    float bias[4];

    #pragma unroll 1
    for (int l = 0; l < NLAYERS; l++) {
        // ---- load this layer's weight fragments into registers ----
        if (l == 0) {
            #pragma unroll
            for (int gt = 0; gt < 4; gt++) {
                const float* wr = Whh0 + (size_t)(gt*64 + hh)*HID;
                whh[gt][0] = load_w8(wr + q*8);
                whh[gt][1] = load_w8(wr + 32 + q*8);
            }
        } else {
            const float* wi = WihR + (size_t)(l-1)*NG*HID;
            const float* wh = WhhR + (size_t)(l-1)*NG*HID;
            #pragma unroll
            for (int gt = 0; gt < 4; gt++) {
                int g = gt*64 + hh;
                wih[gt][0] = load_w8(wi + (size_t)g*HID + q*8);
                wih[gt][1] = load_w8(wi + (size_t)g*HID + 32 + q*8);
                whh[gt][0] = load_w8(wh + (size_t)g*HID + q*8);
                whh[gt][1] = load_w8(wh + (size_t)g*HID + 32 + q*8);
                bias[gt] = bihR[(size_t)(l-1)*NG + g] + bhhR[(size_t)(l-1)*NG + g];
            }
        }
        float c[4] = {0.f, 0.f, 0.f, 0.f};
        f32x4 xpn[4];
        if (l == 0) {   // prefetch xp0 for t=0
            #pragma unroll
            for (int gt = 0; gt < 4; gt++)
                xpn[gt] = *(const f32x4*)(xp0 + ((size_t)(gt*64 + hh))*NBATCH + b0 + q*4);
        }

        #pragma unroll 1
        for (int t = 0; t < T_SEQ; t++) {
            f32x4 acc[4];
            if (l == 0) {
                #pragma unroll
                for (int gt = 0; gt < 4; gt++) acc[gt] = xpn[gt];
                if (t < T_SEQ-1) {   // prefetch next timestep's xp0 (hides HBM latency)
                    #pragma unroll
                    for (int gt = 0; gt < 4; gt++)
                        xpn[gt] = *(const f32x4*)(xp0 + (((size_t)(t+1))*NG + gt*64 + hh)*NBATCH + b0 + q*4);
                }
            } else {
                #pragma unroll
                for (int gt = 0; gt < 4; gt++) acc[gt] = (f32x4){bias[gt],bias[gt],bias[gt],bias[gt]};
            }
            // read A fragments BEFORE barrier (in-place buffer: read-then-write)
            bf16x8 a_in0, a_in1, a_h0, a_h1;
            if (l > 0) {
                a_in0 = *(const bf16x8*)&seq[t][col][q*8];
                a_in1 = *(const bf16x8*)&seq[t][col][32 + q*8];
            }
            if (t > 0) {
                a_h0 = *(const bf16x8*)&seq[t-1][col][q*8];
                a_h1 = *(const bf16x8*)&seq[t-1][col][32 + q*8];
            }
            __syncthreads();   // all reads of seq[t]/seq[t-1] done before writes below
            if (l > 0) {
                #pragma unroll
                for (int gt = 0; gt < 4; gt++) {
                    acc[gt] = __builtin_amdgcn_mfma_f32_16x16x32_bf16(a_in0, wih[gt][0], acc[gt], 0,0,0);
                    acc[gt] = __builtin_amdgcn_mfma_f32_16x16x32_bf16(a_in1, wih[gt][1], acc[gt], 0,0,0);
                }
            }
            if (t > 0) {
                #pragma unroll
                for (int gt = 0; gt < 4; gt++) {
                    acc[gt] = __builtin_amdgcn_mfma_f32_16x16x32_bf16(a_h0, whh[gt][0], acc[gt], 0,0,0);
                    acc[gt] = __builtin_amdgcn_mfma_f32_16x16x32_bf16(a_h1, whh[gt][1], acc[gt], 0,0,0);
                }
            }
            // gate math: lane (q,col) holds gates i,f,g,o of (b=4q+r, h=hh)
            #pragma unroll
            for (int r = 0; r < 4; r++) {
                float ig = sigm(acc[0][r]);
                float fg = sigm(acc[1][r]);
                float gg = tanh_f(acc[2][r]);
                float og = sigm(acc[3][r]);
                float cn = fg*c[r] + ig*gg;
                c[r] = cn;
                float hn = og * tanh_f(cn);
                seq[t][q*4 + r][hh] = f2bf(hn);
                if (t == T_SEQ-1) {   // layer's final state -> fp32 outputs
                    size_t idx = ((size_t)l*NBATCH + b0 + q*4 + r)*HID + hh;
                    h_n[idx] = hn;
                    c_n[idx] = cn;
                }
            }
            __syncthreads();   // h(t) visible before next step's reads
        }
    }
    // lstm_out = hs[:, -1(batch=4095), :] @ Wlin^T + blin -- only last block
    if (b0 == NBATCH - 16 && tid < T_SEQ*NOUT) {
        int ti = tid / NOUT, o = tid - ti*NOUT;
        float s = blin[o];
        #pragma unroll
        for (int k = 0; k < HID; k++)
            s += bf2f(seq[ti][15][k]) * Wlin[o*HID + k];
        out[tid] = s;
    }
}

extern "C" void kernel_launch(void* const* d_in, const int* in_sizes, int n_in,
                              void* d_out, int out_size, void* d_ws, size_t ws_size,
                              hipStream_t stream) {
    const float* x    = (const float*)d_in[0];
    const float* Wih0 = (const float*)d_in[1];
    const float* Whh0 = (const float*)d_in[2];
    const float* bih0 = (const float*)d_in[3];
    const float* bhh0 = (const float*)d_in[4];
    const float* WihR = (const float*)d_in[5];
    const float* WhhR = (const float*)d_in[6];
    const float* bihR = (const float*)d_in[7];
    const float* bhhR = (const float*)d_in[8];
    const float* Wlin = (const float*)d_in[9];
    const float* blin = (const float*)d_in[10];
    float* out = (float*)d_out;
    float* xp0 = (float*)d_ws;   // 25*256*4096 fp32 = 104.8 MB

    xp0_gemm<<<dim3(800), dim3(256), 0, stream>>>(x, Wih0, bih0, bhh0, xp0);
    lstm_persist<<<dim3(NBATCH/16), dim3(256), 0, stream>>>(
        Whh0, WihR, WhhR, bihR, bhhR, Wlin, blin, xp0, out);
}

// Round 2
// 1038.544 us; speedup vs baseline: 1.3534x; 1.3534x over previous
//
#include <hip/hip_runtime.h>

#define T_SEQ 25
#define NBATCH 4096
#define D_IN 500
#define HID 64
#define NG 256
#define NLAYERS 25
#define NOUT 10

typedef __attribute__((ext_vector_type(8))) short bf16x8;
typedef __attribute__((ext_vector_type(4))) short bf16x4;
typedef __attribute__((ext_vector_type(4))) float f32x4;

#define LOG2E 1.4426950408889634f

__device__ __forceinline__ short f2bf(float f) {
    union { float f; unsigned u; } v; v.f = f;
    unsigned u = v.u + 0x7FFFu + ((v.u >> 16) & 1u);   // RNE
    return (short)(u >> 16);
}
__device__ __forceinline__ float bf2f(short s) {
    union { unsigned u; float f; } v;
    v.u = ((unsigned)(unsigned short)s) << 16;
    return v.f;
}
__device__ __forceinline__ bf16x8 cvt8(f32x4 a, f32x4 b) {
    bf16x8 r;
    r[0]=f2bf(a[0]); r[1]=f2bf(a[1]); r[2]=f2bf(a[2]); r[3]=f2bf(a[3]);
    r[4]=f2bf(b[0]); r[5]=f2bf(b[1]); r[6]=f2bf(b[2]); r[7]=f2bf(b[3]);
    return r;
}
__device__ __forceinline__ bf16x8 load_w8(const float* p) {
    const f32x4* p4 = (const f32x4*)p;
    return cvt8(p4[0], p4[1]);
}
// Fast activations: single-instruction v_exp_f32 / v_rcp_f32 (no IEEE div seq)
__device__ __forceinline__ float sigm(float x) {
    return __builtin_amdgcn_rcpf(1.f + __builtin_amdgcn_exp2f(-LOG2E * x));
}
__device__ __forceinline__ float tanh_f(float x) {
    return 1.f - 2.f * __builtin_amdgcn_rcpf(__builtin_amdgcn_exp2f(2.f * LOG2E * x) + 1.f);
}

// ---------------------------------------------------------------------------
// Kernel W: pre-convert W_ih0 (256x500 fp32) -> bf16 [256][512], zero-padded K.
// ---------------------------------------------------------------------------
__global__ __launch_bounds__(256)
void conv_w(const float* __restrict__ W, short* __restrict__ wbf) {
    int idx = blockIdx.x * 256 + threadIdx.x;      // 512 blocks -> 131072
    int row = idx >> 9, k = idx & 511;
    wbf[idx] = (k < D_IN) ? f2bf(W[row * D_IN + k]) : (short)0;
}

// ---------------------------------------------------------------------------
// Kernel A: xp0[t][g][b] = sum_k x[t][b][k]*Wih0[g][k] + bih0[g] + bhh0[g]
// M-tile 128 (b within one t), N = 256 full, K = 500 padded to 512.
// Output bf16, layout [t][g][b] so kernel B reads 8B/lane contiguous in b.
// ---------------------------------------------------------------------------
__global__ __launch_bounds__(256, 1)
void xp0_gemm(const float* __restrict__ x, const short* __restrict__ wbf,
              const float* __restrict__ bih0, const float* __restrict__ bhh0,
              short* __restrict__ xp0b) {
    __shared__ short a_sh[128][40];   // pad 32->40 shorts
    __shared__ short b_sh[256][40];
    const int tid  = threadIdx.x;
    const int wv   = tid >> 6, lane = tid & 63, col = lane & 15, q = lane >> 4;
    const int t    = blockIdx.x >> 5;          // 32 M-tiles per t
    const int b0   = (blockIdx.x & 31) << 7;   // 128-row b tile

    f32x4 acc[2][16];
    #pragma unroll
    for (int nt = 0; nt < 16; nt++) {
        int g = nt*16 + col;
        float bv = bih0[g] + bhh0[g];
        acc[0][nt] = (f32x4){bv,bv,bv,bv};
        acc[1][nt] = acc[0][nt];
    }

    const int arow = tid >> 1;
    const int akh  = (tid & 1) << 4;           // 0 or 16
    const float* axp = x + ((size_t)t*NBATCH + b0 + arow)*D_IN + akh;
    const short* bwp = wbf + (size_t)tid*512;

    #pragma unroll 1
    for (int kc = 0; kc < 16; kc++) {
        const int kb = kc*32;
        if (kc < 15) {                          // A fully in-bounds
            const f32x4* s = (const f32x4*)(axp + kb);
            f32x4 v0 = s[0], v1 = s[1], v2 = s[2], v3 = s[3];
            *(bf16x8*)&a_sh[arow][akh]     = cvt8(v0, v1);
            *(bf16x8*)&a_sh[arow][akh + 8] = cvt8(v2, v3);
        } else {                                // K tail for A: 480..499 valid
            #pragma unroll
            for (int i = 0; i < 16; i++) {
                int k = kb + akh + i;
                a_sh[arow][akh + i] = (k < D_IN) ? f2bf(axp[kb + i]) : (short)0;
            }
        }
        {   // B staging: pure bf16 16B copies, no conversion
            const bf16x8* src = (const bf16x8*)(bwp + kb);
            *(bf16x8*)&b_sh[tid][0]  = src[0];
            *(bf16x8*)&b_sh[tid][8]  = src[1];
            *(bf16x8*)&b_sh[tid][16] = src[2];
            *(bf16x8*)&b_sh[tid][24] = src[3];
        }
        __syncthreads();
        bf16x8 a0 = *(const bf16x8*)&a_sh[wv*32      + col][q*8];
        bf16x8 a1 = *(const bf16x8*)&a_sh[wv*32 + 16 + col][q*8];
        #pragma unroll
        for (int nt = 0; nt < 16; nt++) {
            bf16x8 bf = *(const bf16x8*)&b_sh[nt*16 + col][q*8];
            acc[0][nt] = __builtin_amdgcn_mfma_f32_16x16x32_bf16(a0, bf, acc[0][nt], 0,0,0);
            acc[1][nt] = __builtin_amdgcn_mfma_f32_16x16x32_bf16(a1, bf, acc[1][nt], 0,0,0);
        }
        __syncthreads();
    }
    #pragma unroll
    for (int ms = 0; ms < 2; ms++) {
        #pragma unroll
        for (int nt = 0; nt < 16; nt++) {
            int g = nt*16 + col;
            int b = b0 + wv*32 + ms*16 + q*4;
            bf16x4 o;
            o[0]=f2bf(acc[ms][nt][0]); o[1]=f2bf(acc[ms][nt][1]);
            o[2]=f2bf(acc[ms][nt][2]); o[3]=f2bf(acc[ms][nt][3]);
            *(bf16x4*)(xp0b + ((size_t)t*NG + g)*NBATCH + b) = o;
        }
    }
}

// ---------------------------------------------------------------------------
// Kernel B: persistent per-batch-slice LSTM. 256 WGs x 256 thr; WG owns 16
// batch rows for all 25 layers x 25 timesteps. Wave w owns h-slice
// [16w,16w+16): its 4 N-tiles are the 4 gate types for those h (gate math
// fully in-register). h sequence ping-pongs between two LDS buffers by
// layer parity -> ONE barrier per step (write-visibility only).
// ---------------------------------------------------------------------------
__global__ __launch_bounds__(256, 1)
void lstm_persist(const float* __restrict__ Whh0,
                  const float* __restrict__ WihR, const float* __restrict__ WhhR,
                  const float* __restrict__ bihR, const float* __restrict__ bhhR,
                  const float* __restrict__ Wlin, const float* __restrict__ blin,
                  const short* __restrict__ xp0b, float* __restrict__ out) {
    __shared__ short seq[2][T_SEQ][16][72];   // ping-pong by layer parity
    const int tid = threadIdx.x;
    const int wv  = tid >> 6, lane = tid & 63, col = lane & 15, q = lane >> 4;
    const int b0  = blockIdx.x << 4;
    const int hh  = wv*16 + col;
    float* __restrict__ h_n = out + 250;
    float* __restrict__ c_n = out + 250 + (size_t)NLAYERS*NBATCH*HID;

    bf16x8 wih[4][2], whh[4][2];
    float bias[4];

    #pragma unroll 1
    for (int l = 0; l < NLAYERS; l++) {
        const int rb = l & 1;          // read buffer (prev layer's output)
        const int wb = rb ^ 1;         // write buffer (this layer's output)
        if (l == 0) {
            #pragma unroll
            for (int gt = 0; gt < 4; gt++) {
                const float* wr = Whh0 + (size_t)(gt*64 + hh)*HID;
                whh[gt][0] = load_w8(wr + q*8);
                whh[gt][1] = load_w8(wr + 32 + q*8);
            }
        } else {
            const float* wi = WihR + (size_t)(l-1)*NG*HID;
            const float* wh = WhhR + (size_t)(l-1)*NG*HID;
            #pragma unroll
            for (int gt = 0; gt < 4; gt++) {
                int g = gt*64 + hh;
                wih[gt][0] = load_w8(wi + (size_t)g*HID + q*8);
                wih[gt][1] = load_w8(wi + (size_t)g*HID + 32 + q*8);
                whh[gt][0] = load_w8(wh + (size_t)g*HID + q*8);
                whh[gt][1] = load_w8(wh + (size_t)g*HID + 32 + q*8);
                bias[gt] = bihR[(size_t)(l-1)*NG + g] + bhhR[(size_t)(l-1)*NG + g];
            }
        }
        float c[4] = {0.f, 0.f, 0.f, 0.f};
        bf16x4 xpn[4];
        if (l == 0) {
            #pragma unroll
            for (int gt = 0; gt < 4; gt++)
                xpn[gt] = *(const bf16x4*)(xp0b + ((size_t)(gt*64 + hh))*NBATCH + b0 + q*4);
        }

        #pragma unroll 1
        for (int t = 0; t < T_SEQ; t++) {
            f32x4 acc[4];
            if (l == 0) {
                #pragma unroll
                for (int gt = 0; gt < 4; gt++) {
                    acc[gt][0]=bf2f(xpn[gt][0]); acc[gt][1]=bf2f(xpn[gt][1]);
                    acc[gt][2]=bf2f(xpn[gt][2]); acc[gt][3]=bf2f(xpn[gt][3]);
                }
                if (t < T_SEQ-1) {   // prefetch next timestep's xp0
                    #pragma unroll
                    for (int gt = 0; gt < 4; gt++)
                        xpn[gt] = *(const bf16x4*)(xp0b + (((size_t)(t+1))*NG + gt*64 + hh)*NBATCH + b0 + q*4);
                }
            } else {
                #pragma unroll
                for (int gt = 0; gt < 4; gt++) acc[gt] = (f32x4){bias[gt],bias[gt],bias[gt],bias[gt]};
            }
            if (l > 0) {
                bf16x8 a_in0 = *(const bf16x8*)&seq[rb][t][col][q*8];
                bf16x8 a_in1 = *(const bf16x8*)&seq[rb][t][col][32 + q*8];
                #pragma unroll
                for (int gt = 0; gt < 4; gt++) {
                    acc[gt] = __builtin_amdgcn_mfma_f32_16x16x32_bf16(a_in0, wih[gt][0], acc[gt], 0,0,0);
                    acc[gt] = __builtin_amdgcn_mfma_f32_16x16x32_bf16(a_in1, wih[gt][1], acc[gt], 0,0,0);
                }
            }
            if (t > 0) {
                bf16x8 a_h0 = *(const bf16x8*)&seq[wb][t-1][col][q*8];
                bf16x8 a_h1 = *(const bf16x8*)&seq[wb][t-1][col][32 + q*8];
                #pragma unroll
                for (int gt = 0; gt < 4; gt++) {
                    acc[gt] = __builtin_amdgcn_mfma_f32_16x16x32_bf16(a_h0, whh[gt][0], acc[gt], 0,0,0);
                    acc[gt] = __builtin_amdgcn_mfma_f32_16x16x32_bf16(a_h1, whh[gt][1], acc[gt], 0,0,0);
                }
            }
            // gate math: lane (q,col) holds gates i,f,g,o of (b=4q+r, h=hh)
            #pragma unroll
            for (int r = 0; r < 4; r++) {
                float ig = sigm(acc[0][r]);
                float fg = sigm(acc[1][r]);
                float gg = tanh_f(acc[2][r]);
                float og = sigm(acc[3][r]);
                float cn = fg*c[r] + ig*gg;
                c[r] = cn;
                float hn = og * tanh_f(cn);
                seq[wb][t][q*4 + r][hh] = f2bf(hn);
                if (t == T_SEQ-1) {
                    size_t idx = ((size_t)l*NBATCH + b0 + q*4 + r)*HID + hh;
                    h_n[idx] = hn;
                    c_n[idx] = cn;
                }
            }
            __syncthreads();   // h(t) visible for next step's a_h reads
        }
    }
    // lstm_out = hs[:, -1(batch idx 4095), :] @ Wlin^T + blin — last block only.
    // Last layer (l=24) wrote buffer (24+1)&1 = 1.
    if (b0 == NBATCH - 16 && tid < T_SEQ*NOUT) {
        int ti = tid / NOUT, o = tid - ti*NOUT;
        float s = blin[o];
        #pragma unroll
        for (int k = 0; k < HID; k++)
            s += bf2f(seq[1][ti][15][k]) * Wlin[o*HID + k];
        out[tid] = s;
    }
}

extern "C" void kernel_launch(void* const* d_in, const int* in_sizes, int n_in,
                              void* d_out, int out_size, void* d_ws, size_t ws_size,
                              hipStream_t stream) {
    const float* x    = (const float*)d_in[0];
    const float* Wih0 = (const float*)d_in[1];
    const float* Whh0 = (const float*)d_in[2];
    const float* bih0 = (const float*)d_in[3];
    const float* bhh0 = (const float*)d_in[4];
    const float* WihR = (const float*)d_in[5];
    const float* WhhR = (const float*)d_in[6];
    const float* bihR = (const float*)d_in[7];
    const float* bhhR = (const float*)d_in[8];
    const float* Wlin = (const float*)d_in[9];
    const float* blin = (const float*)d_in[10];
    float* out = (float*)d_out;
    short* xp0b = (short*)d_ws;                        // 25*256*4096 bf16 = 52.4 MB
    short* wbf  = xp0b + (size_t)T_SEQ*NG*NBATCH;      // 256*512 bf16 = 0.26 MB

    conv_w<<<dim3(512), dim3(256), 0, stream>>>(Wih0, wbf);
    xp0_gemm<<<dim3(800), dim3(256), 0, stream>>>(x, wbf, bih0, bhh0, xp0b);
    lstm_persist<<<dim3(NBATCH/16), dim3(256), 0, stream>>>(
        Whh0, WihR, WhhR, bihR, bhhR, Wlin, blin, xp0b, out);
}

// Round 3
// 834.920 us; speedup vs baseline: 1.6835x; 1.2439x over previous
//
#include <hip/hip_runtime.h>

#define T_SEQ 25
#define NBATCH 4096
#define D_IN 500
#define HID 64
#define NG 256
#define NLAYERS 25
#define NOUT 10

typedef __attribute__((ext_vector_type(8))) short bf16x8;
typedef __attribute__((ext_vector_type(4))) short bf16x4;
typedef __attribute__((ext_vector_type(4))) float f32x4;

#define LOG2E 1.4426950408889634f

__device__ __forceinline__ short f2bf(float f) {
    union { float f; unsigned u; } v; v.f = f;
    unsigned u = v.u + 0x7FFFu + ((v.u >> 16) & 1u);   // RNE
    return (short)(u >> 16);
}
__device__ __forceinline__ float bf2f(short s) {
    union { unsigned u; float f; } v;
    v.u = ((unsigned)(unsigned short)s) << 16;
    return v.f;
}
__device__ __forceinline__ bf16x8 cvt8(f32x4 a, f32x4 b) {
    bf16x8 r;
    r[0]=f2bf(a[0]); r[1]=f2bf(a[1]); r[2]=f2bf(a[2]); r[3]=f2bf(a[3]);
    r[4]=f2bf(b[0]); r[5]=f2bf(b[1]); r[6]=f2bf(b[2]); r[7]=f2bf(b[3]);
    return r;
}
__device__ __forceinline__ float sigm(float x) {
    return __builtin_amdgcn_rcpf(1.f + __builtin_amdgcn_exp2f(-LOG2E * x));
}
__device__ __forceinline__ float tanh_f(float x) {
    return 1.f - 2.f * __builtin_amdgcn_rcpf(__builtin_amdgcn_exp2f(2.f * LOG2E * x) + 1.f);
}

// ---------------------------------------------------------------------------
// prep: one elementwise pass converting all weights to bf16 + bias sums.
//   wbf   [256][512]  = W_ih0 zero-padded K (bf16)
//   whh0b [256][64], wihRb/whhRb [24][256][64] (bf16), bsum [24][256] (f32)
// ---------------------------------------------------------------------------
__global__ __launch_bounds__(256)
void prep(const float* __restrict__ Wih0, const float* __restrict__ Whh0,
          const float* __restrict__ WihR, const float* __restrict__ WhhR,
          const float* __restrict__ bihR, const float* __restrict__ bhhR,
          short* __restrict__ wbf, short* __restrict__ whh0b,
          short* __restrict__ wihRb, short* __restrict__ whhRb,
          float* __restrict__ bsum) {
    int idx = blockIdx.x * 256 + threadIdx.x;
    if (idx < 131072) {
        int row = idx >> 9, k = idx & 511;
        wbf[idx] = (k < D_IN) ? f2bf(Wih0[row * D_IN + k]) : (short)0;
    } else if (idx < 147456) {
        int j = idx - 131072; whh0b[j] = f2bf(Whh0[j]);
    } else if (idx < 540672) {
        int j = idx - 147456; wihRb[j] = f2bf(WihR[j]);
    } else if (idx < 933888) {
        int j = idx - 540672; whhRb[j] = f2bf(WhhR[j]);
    } else if (idx < 940032) {
        int j = idx - 933888; bsum[j] = bihR[j] + bhhR[j];
    }
}

// ---------------------------------------------------------------------------
// Kernel A: xp0[t][g][b] (bf16) = x·W_ih0^T + bih0 + bhh0.
// No LDS, no barriers: A fragments loaded straight from x rows (cvt in-reg),
// B fragments loaded straight from the 256 KB bf16 weight image (L1/L2-hot).
// ---------------------------------------------------------------------------
__global__ __launch_bounds__(256, 1)
void xp0_gemm(const float* __restrict__ x, const short* __restrict__ wbf,
              const float* __restrict__ bih0, const float* __restrict__ bhh0,
              short* __restrict__ xp0b) {
    const int tid = threadIdx.x;
    const int wv = tid >> 6, lane = tid & 63, col = lane & 15, q = lane >> 4;
    const int t  = blockIdx.x >> 5;           // 32 M-tiles per t
    const int b0 = (blockIdx.x & 31) << 7;    // 128-row b tile

    f32x4 acc[2][16];
    #pragma unroll
    for (int nt = 0; nt < 16; nt++) {
        int g = nt*16 + col;
        float bv = bih0[g] + bhh0[g];
        acc[0][nt] = (f32x4){bv,bv,bv,bv};
        acc[1][nt] = acc[0][nt];
    }
    const float* xrow0 = x + ((size_t)t*NBATCH + b0 + wv*32 + col)*D_IN;
    const float* xrow1 = xrow0 + 16*(size_t)D_IN;

    #pragma unroll 3
    for (int kc = 0; kc < 15; kc++) {
        const int ko = kc*32 + q*8;
        const f32x4* p0 = (const f32x4*)(xrow0 + ko);
        const f32x4* p1 = (const f32x4*)(xrow1 + ko);
        bf16x8 a0 = cvt8(p0[0], p0[1]);
        bf16x8 a1 = cvt8(p1[0], p1[1]);
        #pragma unroll
        for (int nt = 0; nt < 16; nt++) {
            bf16x8 bfr = *(const bf16x8*)(wbf + (size_t)(nt*16+col)*512 + kc*32 + q*8);
            acc[0][nt] = __builtin_amdgcn_mfma_f32_16x16x32_bf16(a0, bfr, acc[0][nt], 0,0,0);
            acc[1][nt] = __builtin_amdgcn_mfma_f32_16x16x32_bf16(a1, bfr, acc[1][nt], 0,0,0);
        }
    }
    {   // K tail kc=15: k=480..511, valid < 500 (f32x4 @496 stays in-row-bounds)
        f32x4 z = (f32x4){0.f,0.f,0.f,0.f};
        f32x4 lo0=z, hi0=z, lo1=z, hi1=z;
        const int ko = 480 + q*8;
        if (q < 2) {
            lo0 = *(const f32x4*)(xrow0 + ko); hi0 = *(const f32x4*)(xrow0 + ko + 4);
            lo1 = *(const f32x4*)(xrow1 + ko); hi1 = *(const f32x4*)(xrow1 + ko + 4);
        } else if (q == 2) {
            lo0 = *(const f32x4*)(xrow0 + 496);
            lo1 = *(const f32x4*)(xrow1 + 496);
        }
        bf16x8 a0 = cvt8(lo0, hi0);
        bf16x8 a1 = cvt8(lo1, hi1);
        #pragma unroll
        for (int nt = 0; nt < 16; nt++) {
            bf16x8 bfr = *(const bf16x8*)(wbf + (size_t)(nt*16+col)*512 + 480 + q*8);
            acc[0][nt] = __builtin_amdgcn_mfma_f32_16x16x32_bf16(a0, bfr, acc[0][nt], 0,0,0);
            acc[1][nt] = __builtin_amdgcn_mfma_f32_16x16x32_bf16(a1, bfr, acc[1][nt], 0,0,0);
        }
    }
    #pragma unroll
    for (int ms = 0; ms < 2; ms++) {
        #pragma unroll
        for (int nt = 0; nt < 16; nt++) {
            int g = nt*16 + col;
            int b = b0 + wv*32 + ms*16 + q*4;
            bf16x4 o;
            o[0]=f2bf(acc[ms][nt][0]); o[1]=f2bf(acc[ms][nt][1]);
            o[2]=f2bf(acc[ms][nt][2]); o[3]=f2bf(acc[ms][nt][3]);
            *(bf16x4*)(xp0b + ((size_t)t*NG + g)*NBATCH + b) = o;
        }
    }
}

// ---------------------------------------------------------------------------
// Kernel B: persistent LSTM. 256 WGs x 256 thr; WG owns 16 batch rows.
// Per layer, T is processed in chunks of 5: a pipelined burst computes 5
// timesteps' input projections (40 MFMAs, deep ILP) into registers, then 5
// lean recurrent steps (2 ds_read + 8 MFMA + gates + 1 barrier each).
// Single in-place seq buffer: seq[t-1] doubles as the recurrent h source.
// ---------------------------------------------------------------------------
__global__ __launch_bounds__(256, 1)
void lstm_persist(const short* __restrict__ whh0b, const short* __restrict__ wihRb,
                  const short* __restrict__ whhRb, const float* __restrict__ bsum,
                  const float* __restrict__ Wlin, const float* __restrict__ blin,
                  const short* __restrict__ xp0b, float* __restrict__ out) {
    __shared__ short seq[T_SEQ * 16 * 72];   // [t][b(16)][h], stride 72 (16B-aligned rows)
    const int tid = threadIdx.x;
    const int wv = tid >> 6, lane = tid & 63, col = lane & 15, q = lane >> 4;
    const int b0 = blockIdx.x << 4;
    const int hh = wv*16 + col;
    float* __restrict__ h_n = out + 250;
    float* __restrict__ c_n = out + 250 + (size_t)NLAYERS*NBATCH*HID;

    bf16x8 wih[4][2], whh[4][2];
    float bias[4];

    #pragma unroll 1
    for (int l = 0; l < NLAYERS; l++) {
        if (l == 0) {
            #pragma unroll
            for (int gt = 0; gt < 4; gt++) {
                const short* wr = whh0b + (size_t)(gt*64 + hh)*64;
                whh[gt][0] = *(const bf16x8*)(wr + q*8);
                whh[gt][1] = *(const bf16x8*)(wr + 32 + q*8);
            }
        } else {
            const short* wi = wihRb + (size_t)(l-1)*16384;
            const short* wh = whhRb + (size_t)(l-1)*16384;
            #pragma unroll
            for (int gt = 0; gt < 4; gt++) {
                int g = gt*64 + hh;
                wih[gt][0] = *(const bf16x8*)(wi + (size_t)g*64 + q*8);
                wih[gt][1] = *(const bf16x8*)(wi + (size_t)g*64 + 32 + q*8);
                whh[gt][0] = *(const bf16x8*)(wh + (size_t)g*64 + q*8);
                whh[gt][1] = *(const bf16x8*)(wh + (size_t)g*64 + 32 + q*8);
                bias[gt] = bsum[(size_t)(l-1)*NG + g];
            }
        }
        float c[4] = {0.f, 0.f, 0.f, 0.f};

        #pragma unroll 1
        for (int j = 0; j < 5; j++) {
            const int t0 = j*5;
            f32x4 pre[5][4];
            if (l == 0) {   // xp0 already has proj+bias: just load+widen (20 loads in flight)
                #pragma unroll
                for (int i = 0; i < 5; i++) {
                    #pragma unroll
                    for (int gt = 0; gt < 4; gt++) {
                        bf16x4 v = *(const bf16x4*)(xp0b +
                            ((size_t)(t0+i)*NG + gt*64 + hh)*NBATCH + b0 + q*4);
                        f32x4 p;
                        p[0]=bf2f(v[0]); p[1]=bf2f(v[1]); p[2]=bf2f(v[2]); p[3]=bf2f(v[3]);
                        pre[i][gt] = p;
                    }
                }
            } else {        // burst input projection: 40 MFMAs, 20 indep chains
                #pragma unroll
                for (int i = 0; i < 5; i++) {
                    const short* sp = &seq[((t0+i)*16 + col)*72];
                    bf16x8 a0 = *(const bf16x8*)(sp + q*8);
                    bf16x8 a1 = *(const bf16x8*)(sp + 32 + q*8);
                    #pragma unroll
                    for (int gt = 0; gt < 4; gt++) {
                        f32x4 p = (f32x4){bias[gt],bias[gt],bias[gt],bias[gt]};
                        p = __builtin_amdgcn_mfma_f32_16x16x32_bf16(a0, wih[gt][0], p, 0,0,0);
                        p = __builtin_amdgcn_mfma_f32_16x16x32_bf16(a1, wih[gt][1], p, 0,0,0);
                        pre[i][gt] = p;
                    }
                }
            }
            __syncthreads();   // all burst reads of seq[t0..t0+4] done before overwrite

            #pragma unroll
            for (int i = 0; i < 5; i++) {
                const int t = t0 + i;
                f32x4 acc4[4];
                #pragma unroll
                for (int gt = 0; gt < 4; gt++) acc4[gt] = pre[i][gt];
                if (i > 0 || j > 0) {   // h(t-1) lives in seq[t-1] (overwritten in place)
                    const short* hp = &seq[((t-1)*16 + col)*72];
                    bf16x8 h0 = *(const bf16x8*)(hp + q*8);
                    bf16x8 h1 = *(const bf16x8*)(hp + 32 + q*8);
                    #pragma unroll
                    for (int gt = 0; gt < 4; gt++) {
                        acc4[gt] = __builtin_amdgcn_mfma_f32_16x16x32_bf16(h0, whh[gt][0], acc4[gt], 0,0,0);
                        acc4[gt] = __builtin_amdgcn_mfma_f32_16x16x32_bf16(h1, whh[gt][1], acc4[gt], 0,0,0);
                    }
                }
                #pragma unroll
                for (int r = 0; r < 4; r++) {
                    float ig = sigm(acc4[0][r]);
                    float fg = sigm(acc4[1][r]);
                    float gg = tanh_f(acc4[2][r]);
                    float og = sigm(acc4[3][r]);
                    float cn = fg*c[r] + ig*gg;
                    c[r] = cn;
                    float hn = og * tanh_f(cn);
                    seq[(t*16 + q*4 + r)*72 + hh] = f2bf(hn);
                    if (i == 4) {
                        if (t == T_SEQ-1) {
                            size_t o = ((size_t)l*NBATCH + b0 + q*4 + r)*HID + hh;
                            h_n[o] = hn;
                            c_n[o] = cn;
                        }
                    }
                }
                __syncthreads();   // h(t) visible for step t+1 / next burst
            }
        }
    }
    // lstm_out = hs[:, batch 4095, :] @ Wlin^T + blin — last block only
    if (b0 == NBATCH - 16 && tid < T_SEQ*NOUT) {
        int ti = tid / NOUT, o = tid - ti*NOUT;
        float s = blin[o];
        #pragma unroll
        for (int k = 0; k < HID; k++)
            s += bf2f(seq[(ti*16 + 15)*72 + k]) * Wlin[o*HID + k];
        out[tid] = s;
    }
}

extern "C" void kernel_launch(void* const* d_in, const int* in_sizes, int n_in,
                              void* d_out, int out_size, void* d_ws, size_t ws_size,
                              hipStream_t stream) {
    const float* x    = (const float*)d_in[0];
    const float* Wih0 = (const float*)d_in[1];
    const float* Whh0 = (const float*)d_in[2];
    const float* bih0 = (const float*)d_in[3];
    const float* bhh0 = (const float*)d_in[4];
    const float* WihR = (const float*)d_in[5];
    const float* WhhR = (const float*)d_in[6];
    const float* bihR = (const float*)d_in[7];
    const float* bhhR = (const float*)d_in[8];
    const float* Wlin = (const float*)d_in[9];
    const float* blin = (const float*)d_in[10];
    float* out = (float*)d_out;

    short* xp0b  = (short*)d_ws;            // 25*256*4096 = 26,214,400 shorts (52.4 MB)
    short* wbf   = xp0b  + 26214400;        // 256*512
    short* whh0b = wbf   + 131072;          // 256*64
    short* wihRb = whh0b + 16384;           // 24*256*64
    short* whhRb = wihRb + 393216;          // 24*256*64
    float* bsum  = (float*)(whhRb + 393216);// 24*256 f32 (byte off 54,296,576 — aligned)

    prep<<<dim3(3672), dim3(256), 0, stream>>>(Wih0, Whh0, WihR, WhhR, bihR, bhhR,
                                               wbf, whh0b, wihRb, whhRb, bsum);
    xp0_gemm<<<dim3(800), dim3(256), 0, stream>>>(x, wbf, bih0, bhh0, xp0b);
    lstm_persist<<<dim3(NBATCH/16), dim3(256), 0, stream>>>(
        whh0b, wihRb, whhRb, bsum, Wlin, blin, xp0b, out);
}

// Round 4
// 716.035 us; speedup vs baseline: 1.9630x; 1.1660x over previous
//
#include <hip/hip_runtime.h>

#define T_SEQ 25
#define NBATCH 4096
#define D_IN 500
#define HID 64
#define NG 256
#define NLAYERS 25
#define NOUT 10

typedef __attribute__((ext_vector_type(8))) short bf16x8;
typedef __attribute__((ext_vector_type(4))) short bf16x4;
typedef __attribute__((ext_vector_type(4))) float f32x4;

#define LOG2E 1.4426950408889634f
#define ROWS 1152              // 16*72 shorts per t-slot
#define RNG_OFF 57600          // ring offset in lds (2*25*1152 = 57600)

__device__ __forceinline__ short f2bf(float f) {
    union { float f; unsigned u; } v; v.f = f;
    unsigned u = v.u + 0x7FFFu + ((v.u >> 16) & 1u);   // RNE
    return (short)(u >> 16);
}
__device__ __forceinline__ float bf2f(short s) {
    union { unsigned u; float f; } v;
    v.u = ((unsigned)(unsigned short)s) << 16;
    return v.f;
}
__device__ __forceinline__ bf16x8 cvt8(f32x4 a, f32x4 b) {
    bf16x8 r;
    r[0]=f2bf(a[0]); r[1]=f2bf(a[1]); r[2]=f2bf(a[2]); r[3]=f2bf(a[3]);
    r[4]=f2bf(b[0]); r[5]=f2bf(b[1]); r[6]=f2bf(b[2]); r[7]=f2bf(b[3]);
    return r;
}

// ---------------------------------------------------------------------------
// prep: weights -> bf16 images. wbf2 is W_ih0 in MFMA B-fragment order:
//   wbf2[((kc*16+nt)*64 + lane)*8 + j] = W[nt*16+(lane&15)][kc*32+(lane>>4)*8+j]
// so xp0_gemm's per-(kc,nt) wave load is one contiguous 1 KB block.
// ---------------------------------------------------------------------------
__global__ __launch_bounds__(256)
void prep(const float* __restrict__ Wih0, const float* __restrict__ Whh0,
          const float* __restrict__ WihR, const float* __restrict__ WhhR,
          const float* __restrict__ bihR, const float* __restrict__ bhhR,
          short* __restrict__ wbf2, short* __restrict__ whh0b,
          short* __restrict__ wihRb, short* __restrict__ whhRb,
          float* __restrict__ bsum) {
    int idx = blockIdx.x * 256 + threadIdx.x;
    if (idx < 131072) {
        int j = idx & 7, lane = (idx >> 3) & 63, nt = (idx >> 9) & 15, kc = idx >> 13;
        int n = nt*16 + (lane & 15);
        int k = kc*32 + (lane >> 4)*8 + j;
        wbf2[idx] = (k < D_IN) ? f2bf(Wih0[n * D_IN + k]) : (short)0;
    } else if (idx < 147456) {
        int j = idx - 131072; whh0b[j] = f2bf(Whh0[j]);
    } else if (idx < 540672) {
        int j = idx - 147456; wihRb[j] = f2bf(WihR[j]);
    } else if (idx < 933888) {
        int j = idx - 540672; whhRb[j] = f2bf(WhhR[j]);
    } else if (idx < 940032) {
        int j = idx - 933888; bsum[j] = bihR[j] + bhhR[j];
    }
}

// ---------------------------------------------------------------------------
// Kernel A: xp0[t][g][b] (bf16) = x·W_ih0^T + bih0 + bhh0.
// A fragments straight from x rows (cvt in-reg); B fragments are contiguous
// 1 KB/wave loads from the fragment-ordered weight image (L2-hot).
// ---------------------------------------------------------------------------
__global__ __launch_bounds__(256, 1)
void xp0_gemm(const float* __restrict__ x, const short* __restrict__ wbf2,
              const float* __restrict__ bih0, const float* __restrict__ bhh0,
              short* __restrict__ xp0b) {
    const int tid = threadIdx.x;
    const int wv = tid >> 6, lane = tid & 63, col = lane & 15, q = lane >> 4;
    const int t  = blockIdx.x >> 5;           // 32 M-tiles per t
    const int b0 = (blockIdx.x & 31) << 7;    // 128-row b tile

    f32x4 acc[2][16];
    #pragma unroll
    for (int nt = 0; nt < 16; nt++) {
        int g = nt*16 + col;
        float bv = bih0[g] + bhh0[g];
        acc[0][nt] = (f32x4){bv,bv,bv,bv};
        acc[1][nt] = acc[0][nt];
    }
    const float* xrow0 = x + ((size_t)t*NBATCH + b0 + wv*32 + col)*D_IN;
    const float* xrow1 = xrow0 + 16*(size_t)D_IN;

    #pragma unroll 3
    for (int kc = 0; kc < 15; kc++) {
        const int ko = kc*32 + q*8;
        const f32x4* p0 = (const f32x4*)(xrow0 + ko);
        const f32x4* p1 = (const f32x4*)(xrow1 + ko);
        bf16x8 a0 = cvt8(p0[0], p0[1]);
        bf16x8 a1 = cvt8(p1[0], p1[1]);
        #pragma unroll
        for (int nt = 0; nt < 16; nt++) {
            bf16x8 bfr = *(const bf16x8*)(wbf2 + ((size_t)(kc*16+nt)*64 + lane)*8);
            acc[0][nt] = __builtin_amdgcn_mfma_f32_16x16x32_bf16(a0, bfr, acc[0][nt], 0,0,0);
            acc[1][nt] = __builtin_amdgcn_mfma_f32_16x16x32_bf16(a1, bfr, acc[1][nt], 0,0,0);
        }
    }
    {   // K tail kc=15: k=480..511, valid < 500
        f32x4 z = (f32x4){0.f,0.f,0.f,0.f};
        f32x4 lo0=z, hi0=z, lo1=z, hi1=z;
        const int ko = 480 + q*8;
        if (q < 2) {
            lo0 = *(const f32x4*)(xrow0 + ko); hi0 = *(const f32x4*)(xrow0 + ko + 4);
            lo1 = *(const f32x4*)(xrow1 + ko); hi1 = *(const f32x4*)(xrow1 + ko + 4);
        } else if (q == 2) {
            lo0 = *(const f32x4*)(xrow0 + 496);
            lo1 = *(const f32x4*)(xrow1 + 496);
        }
        bf16x8 a0 = cvt8(lo0, hi0);
        bf16x8 a1 = cvt8(lo1, hi1);
        #pragma unroll
        for (int nt = 0; nt < 16; nt++) {
            bf16x8 bfr = *(const bf16x8*)(wbf2 + ((size_t)(15*16+nt)*64 + lane)*8);
            acc[0][nt] = __builtin_amdgcn_mfma_f32_16x16x32_bf16(a0, bfr, acc[0][nt], 0,0,0);
            acc[1][nt] = __builtin_amdgcn_mfma_f32_16x16x32_bf16(a1, bfr, acc[1][nt], 0,0,0);
        }
    }
    #pragma unroll
    for (int ms = 0; ms < 2; ms++) {
        #pragma unroll
        for (int nt = 0; nt < 16; nt++) {
            int g = nt*16 + col;
            int b = b0 + wv*32 + ms*16 + q*4;
            bf16x4 o;
            o[0]=f2bf(acc[ms][nt][0]); o[1]=f2bf(acc[ms][nt][1]);
            o[2]=f2bf(acc[ms][nt][2]); o[3]=f2bf(acc[ms][nt][3]);
            *(bf16x4*)(xp0b + ((size_t)t*NG + g)*NBATCH + b) = o;
        }
    }
}

// ---------------------------------------------------------------------------
// Kernel B: layer-paired pipelined LSTM. 256 WGs x 512 thr (8 waves).
// Waves 0-3 (grp A) compute layer 2r+1 reading full buffer P, writing a
// 4-slot LDS ring; waves 4-7 (grp B) compute layer 2r+2 with a 1-step time
// skew, reading the ring, writing full buffer O. P/O ping-pong per round.
// 2 waves/SIMD -> latencies of the two layer chains mutually hide.
// Layer 0 runs solo first (input projection precomputed in xp0b).
// ---------------------------------------------------------------------------

// gate math: lane (q,col) holds gates i,f,g,o of (b=4q+rr, h=hh).
// shared-rcp forms: sig(i)*tanh(g) = (eg-1)/((1+ei)(1+eg)), h = sig(o)*tanh(c)
#define GATES(ACC, OUTB, LAYER, TT)                                            \
    do {                                                                       \
        _Pragma("unroll")                                                      \
        for (int rr = 0; rr < 4; rr++) {                                       \
            float iv = ACC[0][rr], fv = ACC[1][rr];                            \
            float gv = ACC[2][rr], ov = ACC[3][rr];                            \
            float gc = fminf(fmaxf(gv, -30.f), 30.f);                          \
            float ei = __builtin_amdgcn_exp2f(-LOG2E * iv);                    \
            float eg = __builtin_amdgcn_exp2f((2.f*LOG2E) * gc);               \
            float ef = __builtin_amdgcn_exp2f(-LOG2E * fv);                    \
            float it = (eg - 1.f) *                                            \
                __builtin_amdgcn_rcpf((1.f + ei) * (1.f + eg));                \
            float cn = __builtin_amdgcn_rcpf(1.f + ef) * c4[rr] + it;          \
            c4[rr] = cn;                                                       \
            float cc = fminf(fmaxf(cn, -30.f), 30.f);                          \
            float eo = __builtin_amdgcn_exp2f(-LOG2E * ov);                    \
            float ec = __builtin_amdgcn_exp2f((2.f*LOG2E) * cc);               \
            float hn = (ec - 1.f) *                                            \
                __builtin_amdgcn_rcpf((1.f + eo) * (1.f + ec));                \
            lds[(OUTB) + (q*4+rr)*72 + hh] = f2bf(hn);                         \
            if ((TT) == 24) {                                                  \
                size_t oi = ((size_t)(LAYER)*NBATCH + b0 + q*4 + rr)*HID + hh; \
                h_n[oi] = hn; c_n[oi] = cn;                                    \
            }                                                                  \
        }                                                                      \
    } while (0)

__global__ __launch_bounds__(512, 1)
void lstm_persist(const short* __restrict__ whh0b, const short* __restrict__ wihRb,
                  const short* __restrict__ whhRb, const float* __restrict__ bsum,
                  const float* __restrict__ Wlin, const float* __restrict__ blin,
                  const short* __restrict__ xp0b, float* __restrict__ out) {
    __shared__ short lds[2*T_SEQ*ROWS + 4*ROWS];   // P, O, ring = 124.4 KB
    const int tid = threadIdx.x;
    const int wv = tid >> 6, lane = tid & 63, col = lane & 15, q = lane >> 4;
    const int grp = wv >> 2;               // 0 = waves 0-3, 1 = waves 4-7
    const int hh  = (wv & 3)*16 + col;
    const int b0  = blockIdx.x << 4;
    float* __restrict__ h_n = out + 250;
    float* __restrict__ c_n = out + 250 + (size_t)NLAYERS*NBATCH*HID;

    int pOff = T_SEQ*ROWS, oOff = 0;       // solo layer 0 writes oOff=0
    bf16x8 wih[4][2], whh[4][2];
    float bias[4];
    float c4[4] = {0.f,0.f,0.f,0.f};

    // ---------------- solo: layer 0 (group A only; B keeps barrier parity)
    bf16x4 xpn[4];
    if (grp == 0) {
        #pragma unroll
        for (int gt = 0; gt < 4; gt++) {
            const short* wr = whh0b + (size_t)(gt*64 + hh)*64;
            whh[gt][0] = *(const bf16x8*)(wr + q*8);
            whh[gt][1] = *(const bf16x8*)(wr + 32 + q*8);
            xpn[gt] = *(const bf16x4*)(xp0b + ((size_t)(gt*64 + hh))*NBATCH + b0 + q*4);
        }
    }
    for (int t = 0; t < T_SEQ; t++) {
        if (grp == 0) {
            f32x4 acc[4];
            #pragma unroll
            for (int gt = 0; gt < 4; gt++) {
                f32x4 p;
                p[0]=bf2f(xpn[gt][0]); p[1]=bf2f(xpn[gt][1]);
                p[2]=bf2f(xpn[gt][2]); p[3]=bf2f(xpn[gt][3]);
                acc[gt] = p;
            }
            if (t < T_SEQ-1) {
                #pragma unroll
                for (int gt = 0; gt < 4; gt++)
                    xpn[gt] = *(const bf16x4*)(xp0b + (((size_t)(t+1))*NG + gt*64 + hh)*NBATCH + b0 + q*4);
            }
            if (t > 0) {
                const int rb = oOff + (t-1)*ROWS + col*72;
                bf16x8 h0 = *(const bf16x8*)&lds[rb + q*8];
                bf16x8 h1 = *(const bf16x8*)&lds[rb + 32 + q*8];
                #pragma unroll
                for (int gt = 0; gt < 4; gt++) {
                    acc[gt] = __builtin_amdgcn_mfma_f32_16x16x32_bf16(h0, whh[gt][0], acc[gt], 0,0,0);
                    acc[gt] = __builtin_amdgcn_mfma_f32_16x16x32_bf16(h1, whh[gt][1], acc[gt], 0,0,0);
                }
            }
            const int ob = oOff + t*ROWS;
            GATES(acc, ob, 0, t);
        }
        __syncthreads();
    }

    // ---------------- 12 rounds: layers (2r+1 by grp A, 2r+2 by grp B)
    #pragma unroll 1
    for (int r = 0; r < 12; r++) {
        { int tm = pOff; pOff = oOff; oOff = tm; }   // prev round's O becomes P
        const int myl = grp ? (2*r + 2) : (2*r + 1);
        const short* wi = wihRb + (size_t)(myl-1)*16384;
        const short* wh = whhRb + (size_t)(myl-1)*16384;
        #pragma unroll
        for (int gt = 0; gt < 4; gt++) {
            int g = gt*64 + hh;
            wih[gt][0] = *(const bf16x8*)(wi + (size_t)g*64 + q*8);
            wih[gt][1] = *(const bf16x8*)(wi + (size_t)g*64 + 32 + q*8);
            whh[gt][0] = *(const bf16x8*)(wh + (size_t)g*64 + q*8);
            whh[gt][1] = *(const bf16x8*)(wh + (size_t)g*64 + 32 + q*8);
            bias[gt] = bsum[(size_t)(myl-1)*NG + g];
        }
        c4[0]=c4[1]=c4[2]=c4[3]=0.f;

        #pragma unroll 1
        for (int s = 0; s < 26; s++) {
            const int t = s - grp;           // grp B runs 1 step behind
            if (t >= 0 && t < T_SEQ) {
                // A: in = P[t] (full), rec/out = ring; B: in = ring, rec/out = O (full)
                const int in_base  = grp ? (RNG_OFF + (t&3)*ROWS) : (pOff + t*ROWS);
                const int out_base = grp ? (oOff + t*ROWS)        : (RNG_OFF + (t&3)*ROWS);
                f32x4 acc[4];
                #pragma unroll
                for (int gt = 0; gt < 4; gt++)
                    acc[gt] = (f32x4){bias[gt],bias[gt],bias[gt],bias[gt]};
                {
                    const int ib = in_base + col*72;
                    bf16x8 a0 = *(const bf16x8*)&lds[ib + q*8];
                    bf16x8 a1 = *(const bf16x8*)&lds[ib + 32 + q*8];
                    #pragma unroll
                    for (int gt = 0; gt < 4; gt++) {
                        acc[gt] = __builtin_amdgcn_mfma_f32_16x16x32_bf16(a0, wih[gt][0], acc[gt], 0,0,0);
                        acc[gt] = __builtin_amdgcn_mfma_f32_16x16x32_bf16(a1, wih[gt][1], acc[gt], 0,0,0);
                    }
                }
                if (t > 0) {
                    const int rb = (grp ? (oOff + (t-1)*ROWS) : (RNG_OFF + ((t-1)&3)*ROWS)) + col*72;
                    bf16x8 h0 = *(const bf16x8*)&lds[rb + q*8];
                    bf16x8 h1 = *(const bf16x8*)&lds[rb + 32 + q*8];
                    #pragma unroll
                    for (int gt = 0; gt < 4; gt++) {
                        acc[gt] = __builtin_amdgcn_mfma_f32_16x16x32_bf16(h0, whh[gt][0], acc[gt], 0,0,0);
                        acc[gt] = __builtin_amdgcn_mfma_f32_16x16x32_bf16(h1, whh[gt][1], acc[gt], 0,0,0);
                    }
                }
                GATES(acc, out_base, myl, t);
            }
            __syncthreads();
        }
    }

    // lstm_out = hs[:, batch 4095, :] @ Wlin^T + blin — layer 24 sits in O
    if (blockIdx.x == 255 && tid < T_SEQ*NOUT) {
        int ti = tid / NOUT, o = tid - ti*NOUT;
        float s = blin[o];
        #pragma unroll
        for (int k = 0; k < HID; k++)
            s += bf2f(lds[oOff + ti*ROWS + 15*72 + k]) * Wlin[o*HID + k];
        out[tid] = s;
    }
}

extern "C" void kernel_launch(void* const* d_in, const int* in_sizes, int n_in,
                              void* d_out, int out_size, void* d_ws, size_t ws_size,
                              hipStream_t stream) {
    const float* x    = (const float*)d_in[0];
    const float* Wih0 = (const float*)d_in[1];
    const float* Whh0 = (const float*)d_in[2];
    const float* bih0 = (const float*)d_in[3];
    const float* bhh0 = (const float*)d_in[4];
    const float* WihR = (const float*)d_in[5];
    const float* WhhR = (const float*)d_in[6];
    const float* bihR = (const float*)d_in[7];
    const float* bhhR = (const float*)d_in[8];
    const float* Wlin = (const float*)d_in[9];
    const float* blin = (const float*)d_in[10];
    float* out = (float*)d_out;

    short* xp0b  = (short*)d_ws;            // 25*256*4096 = 26,214,400 shorts (52.4 MB)
    short* wbf2  = xp0b  + 26214400;        // 256*512 fragment-ordered
    short* whh0b = wbf2  + 131072;          // 256*64
    short* wihRb = whh0b + 16384;           // 24*256*64
    short* whhRb = wihRb + 393216;          // 24*256*64
    float* bsum  = (float*)(whhRb + 393216);// 24*256 f32

    prep<<<dim3(3672), dim3(256), 0, stream>>>(Wih0, Whh0, WihR, WhhR, bihR, bhhR,
                                               wbf2, whh0b, wihRb, whhRb, bsum);
    xp0_gemm<<<dim3(800), dim3(256), 0, stream>>>(x, wbf2, bih0, bhh0, xp0b);
    lstm_persist<<<dim3(NBATCH/16), dim3(512), 0, stream>>>(
        whh0b, wihRb, whhRb, bsum, Wlin, blin, xp0b, out);
}